// Round 1
// 328.538 us; speedup vs baseline: 1.0181x; 1.0181x over previous
//
#include <hip/hip_runtime.h>
#include <hip/hip_bf16.h>
#include <stdint.h>

typedef float floatx4 __attribute__((ext_vector_type(4)));

// ---------------------------------------------------------------------------
// Threefry-2x32 (JAX-exact): 20 rounds, key injection every 4.
// ---------------------------------------------------------------------------
__host__ __device__ inline uint32_t rotl32(uint32_t x, int r) {
#ifdef __HIP_DEVICE_COMPILE__
  return __builtin_amdgcn_alignbit(x, x, 32 - r);
#else
  return (x << r) | (x >> (32 - r));
#endif
}

__host__ __device__ inline void tf2x32(uint32_t k0, uint32_t k1,
                                       uint32_t x0, uint32_t x1,
                                       uint32_t& o0, uint32_t& o1) {
  const uint32_t k2 = k0 ^ k1 ^ 0x1BD11BDAu;
  x0 += k0; x1 += k1;
#define TFR(r) { x0 += x1; x1 = rotl32(x1, r); x1 ^= x0; }
  TFR(13) TFR(15) TFR(26) TFR(6)
  x0 += k1; x1 += k2 + 1u;
  TFR(17) TFR(29) TFR(16) TFR(24)
  x0 += k2; x1 += k0 + 2u;
  TFR(13) TFR(15) TFR(26) TFR(6)
  x0 += k0; x1 += k1 + 3u;
  TFR(17) TFR(29) TFR(16) TFR(24)
  x0 += k1; x1 += k2 + 4u;
  TFR(13) TFR(15) TFR(26) TFR(6)
  x0 += k2; x1 += k0 + 5u;
#undef TFR
  o0 = x0; o1 = x1;
}

// Partitionable-mode 32-bit random bits, counts (0, i), bits = o0 ^ o1.
// [verified bit-exact vs np ref in prior session rounds 3-8]
__device__ inline uint32_t jax_bits32(uint32_t kA, uint32_t kB, uint32_t i) {
  uint32_t o0, o1;
  tf2x32(kA, kB, 0u, i, o0, o1);
  return o0 ^ o1;
}

__device__ inline float jax_uniform(uint32_t bits) {
  return __uint_as_float((bits >> 9) | 0x3f800000u) - 1.0f;
}

#define D_DIM   4096
#define E_DIM   64
#define EMB     128
#define M_DIM   11008
#define NROWS   4096          // B*S
#define BIN_N   45088768      // NROWS*M_DIM
#define KSPLIT  32            // k-splits in krnA (each 128 wide)
#define CK      32            // staged k-chunk
#define XSTR    284           // verified: 256 rows + quad-spread padding
#define WSTR    68            // verified
#define C2BLKS  172           // M_DIM / 64

// quad-spread address within a k-line: fragment f = v>>3 at f*8 + (f>>2)*4 so
// the 8 fragments of one wave's b128 read start in 8 distinct bank quads.
__device__ inline int qspread(int v) { return v + ((v >> 5) << 2); }

// ---------------------------------------------------------------------------
// Kernel A: logits partials, transposed-LDS outer-product fp32 GEMM.
// Grid (16 row-blocks, 32 k-splits) x 256 thr.  Block: 256 rows x 64 experts
// over 128 K.  Thread (jc=t&7, rg=t>>3): 8 rows x 8 experts, acc[8][8].
// NEW: partials written row-major part[row][ks][e] so krnB streams 8 KB/row.
// ---------------------------------------------------------------------------
__global__ __launch_bounds__(256) void krnA(const float* __restrict__ x,
                                            const float* __restrict__ Wr,
                                            float* __restrict__ part) {
  __shared__ __align__(16) float xsT[CK * XSTR];   // 35.5 KB
  __shared__ __align__(16) float wsT[CK * WSTR];   // 8.5 KB
  const int rb = blockIdx.x, ks = blockIdx.y, t = threadIdx.x;
  const int rbase = rb * 256, kbase0 = ks * 128;
  const int jc = t & 7, rg = t >> 3;
  const int xoff = (rg * 8) + ((rg >> 2) << 2);    // qspread of rg*8
  const int woff = (jc * 8) + ((jc >> 2) << 2);
  float acc[8][8] = {};

  for (int c = 0; c < 4; ++c) {
    const int kbase = kbase0 + c * CK;
    // stage x: 256 rows x 32 k (8 float4 / thread, coalesced)
#pragma unroll
    for (int it = 0; it < 8; ++it) {
      int idx = t + it * 256;
      int row = idx >> 3, kq = idx & 7;
      float4 v = *(const float4*)&x[(size_t)(rbase + row) * D_DIM + kbase + kq * 4];
      int adr = qspread(row);
      xsT[(kq * 4 + 0) * XSTR + adr] = v.x;
      xsT[(kq * 4 + 1) * XSTR + adr] = v.y;
      xsT[(kq * 4 + 2) * XSTR + adr] = v.z;
      xsT[(kq * 4 + 3) * XSTR + adr] = v.w;
    }
    // stage Wr: 64 experts x 32 k (2 float4 / thread)
#pragma unroll
    for (int it = 0; it < 2; ++it) {
      int idx = t + it * 256;
      int e = idx >> 3, kq = idx & 7;
      float4 v = *(const float4*)&Wr[(size_t)e * D_DIM + kbase + kq * 4];
      int adr = qspread(e);
      wsT[(kq * 4 + 0) * WSTR + adr] = v.x;
      wsT[(kq * 4 + 1) * WSTR + adr] = v.y;
      wsT[(kq * 4 + 2) * WSTR + adr] = v.z;
      wsT[(kq * 4 + 3) * WSTR + adr] = v.w;
    }
    __syncthreads();
#pragma unroll
    for (int k = 0; k < CK; ++k) {
      const float* xp = &xsT[k * XSTR + xoff];
      const float* wp = &wsT[k * WSTR + woff];
      floatx4 xa = *(const floatx4*)xp;
      floatx4 xb = *(const floatx4*)(xp + 4);
      floatx4 wa = *(const floatx4*)wp;
      floatx4 wb = *(const floatx4*)(wp + 4);
#pragma unroll
      for (int r = 0; r < 4; ++r)
#pragma unroll
        for (int e = 0; e < 4; ++e) {
          acc[r][e]         += xa[r] * wa[e];
          acc[r][e + 4]     += xa[r] * wb[e];
          acc[r + 4][e]     += xb[r] * wa[e];
          acc[r + 4][e + 4] += xb[r] * wb[e];
        }
    }
    __syncthreads();
  }
  // write partials: part[row][ks][e] (row stride = KSPLIT*E_DIM = 8 KB)
#pragma unroll
  for (int r = 0; r < 8; ++r) {
    float* pp = part + ((size_t)(rbase + rg * 8 + r) * KSPLIT + ks) * E_DIM + jc * 8;
    *(float4*)pp = make_float4(acc[r][0], acc[r][1], acc[r][2], acc[r][3]);
    *(float4*)(pp + 4) = make_float4(acc[r][4], acc[r][5], acc[r][6], acc[r][7]);
  }
}

// ---------------------------------------------------------------------------
// Kernel C2 (fused, was C1+C2): LN+GELU of rnn_state computed in-LDS, then
// P[e][m] = sum_c H[e][c]*Wd[m][c], plus per-block min -> pminLoc[blk].
// ---------------------------------------------------------------------------
__global__ __launch_bounds__(256) void krnC2(const float* __restrict__ rnn,
                                             const float* __restrict__ lnw,
                                             const float* __restrict__ lnb,
                                             const float* __restrict__ Wd,
                                             float* __restrict__ P,
                                             float* __restrict__ pminLoc) {
  __shared__ float4 hs[64][33];    // +1 pad: conflict-free b128 writes
  __shared__ float rmin[4];
  const int t = threadIdx.x;
  // --- LN + GELU: thread t handles 32 elems of row r = t>>2 (q = t&3) ---
  {
    const int r = t >> 2, q = t & 3;
    const float4* rp = (const float4*)(rnn + r * EMB) + q * 8;
    float4 v[8];
    float s = 0.0f;
#pragma unroll
    for (int j = 0; j < 8; ++j) {
      v[j] = rp[j];
      s += v[j].x + v[j].y + v[j].z + v[j].w;
    }
    s += __shfl_xor(s, 1); s += __shfl_xor(s, 2);       // 4-lane group = row
    const float mu = s * (1.0f / 128.0f);
    float qs = 0.0f;
#pragma unroll
    for (int j = 0; j < 8; ++j) {
      float dx = v[j].x - mu, dy = v[j].y - mu, dz = v[j].z - mu, dw = v[j].w - mu;
      qs += dx * dx + dy * dy + dz * dz + dw * dw;
    }
    qs += __shfl_xor(qs, 1); qs += __shfl_xor(qs, 2);
    const float rs = rsqrtf(qs * (1.0f / 128.0f) + 1e-5f);
    const float4* wp = (const float4*)lnw + q * 8;
    const float4* bp = (const float4*)lnb + q * 8;
#pragma unroll
    for (int j = 0; j < 8; ++j) {
      float4 w = wp[j], b = bp[j], g;
      float h;
      h = (v[j].x - mu) * rs * w.x + b.x;
      g.x = 0.5f * h * (1.0f + erff(h * 0.70710678118654752f));
      h = (v[j].y - mu) * rs * w.y + b.y;
      g.y = 0.5f * h * (1.0f + erff(h * 0.70710678118654752f));
      h = (v[j].z - mu) * rs * w.z + b.z;
      g.z = 0.5f * h * (1.0f + erff(h * 0.70710678118654752f));
      h = (v[j].w - mu) * rs * w.w + b.w;
      g.w = 0.5f * h * (1.0f + erff(h * 0.70710678118654752f));
      hs[r][q * 8 + j] = g;
    }
  }
  __syncthreads();
  // --- GEMM (unchanged structure) ---
  const int wv = t >> 6, lane = t & 63;
  const int m = blockIdx.x * 64 + lane;
  const float4* wd4 = (const float4*)(Wd + (size_t)m * EMB);
  float acc[16] = {};
  for (int c4 = 0; c4 < 32; ++c4) {
    float4 w = wd4[c4];
#pragma unroll
    for (int e = 0; e < 16; ++e) {
      float4 h = hs[wv * 16 + e][c4];
      acc[e] += w.x * h.x + w.y * h.y + w.z * h.z + w.w * h.w;
    }
  }
  float mn = acc[0];
#pragma unroll
  for (int e = 0; e < 16; ++e) {
    P[(size_t)(wv * 16 + e) * M_DIM + m] = acc[e];
    mn = fminf(mn, acc[e]);
  }
#pragma unroll
  for (int off = 32; off >= 1; off >>= 1)
    mn = fminf(mn, __shfl_xor(mn, off));
  if (lane == 0) rmin[wv] = mn;
  __syncthreads();
  if (t == 0)
    pminLoc[blockIdx.x] = fminf(fminf(rmin[0], rmin[1]), fminf(rmin[2], rmin[3]));
}

// ---------------------------------------------------------------------------
// Kernel B: reduce 32 partial slices (now contiguous 8 KB per row), add
// gumbel (k1), argmax over 64, write router one-hot + expert index.
// Block 0 additionally folds pminLoc -> K9 (bits-space threshold) once, so
// krnD reads a single precomputed scalar instead of recomputing per-thread.
// ---------------------------------------------------------------------------
__global__ __launch_bounds__(256) void krnB(const float* __restrict__ part,
                                            float* __restrict__ router_out,
                                            int* __restrict__ eidx,
                                            const float* __restrict__ pminLoc,
                                            uint32_t* __restrict__ K9out,
                                            uint32_t K1A, uint32_t K1B) {
  __shared__ float red[4];
  const int t = threadIdx.x;
  const int wv = t >> 6, lane = t & 63;
  const int row = blockIdx.x * 4 + wv;
  float lg = 0.0f;
#pragma unroll
  for (int s = 0; s < KSPLIT; ++s)
    lg += part[((size_t)row * KSPLIT + s) * E_DIM + lane];

  uint32_t jf = (uint32_t)row * 64u + (uint32_t)lane;
  uint32_t bits = jax_bits32(K1A, K1B, jf);
  float u = jax_uniform(bits);
  float inner = -logf(u + 1e-20f);       // precise log: argmax sensitivity
  float g = -logf(inner + 1e-20f);
  float w = (lg + g) * 2.5f;

  float m = w;
#pragma unroll
  for (int off = 32; off >= 1; off >>= 1) m = fmaxf(m, __shfl_xor(m, off));
  unsigned long long msk = __ballot(w == m);
  int arg = __ffsll(msk) - 1;            // first max index == jnp.argmax
  router_out[(size_t)row * E_DIM + lane] = (lane == arg) ? 1.0f : 0.0f;
  if (lane == 0) eidx[row] = arg;

  if (blockIdx.x == 0) {                 // K9 precompute (once per launch)
    float v = (t < C2BLKS) ? pminLoc[t] : 3.0e38f;
#pragma unroll
    for (int off = 32; off >= 1; off >>= 1) v = fminf(v, __shfl_xor(v, off));
    if (lane == 0) red[wv] = v;
    __syncthreads();
    if (t == 0) {
      float pmin = fminf(fminf(red[0], red[1]), fminf(red[2], red[3]));
      float tt = pmin + 2.95f;                       // 0.05 safety slack
      float delta = __expf(-__expf(tt));
      delta = fminf(fmaxf(delta, 1.2e-7f), 0.5f);    // NaN-safe, Ku < 2^23
      uint32_t Ku = (uint32_t)((1.0f - delta) * 8388608.0f);
      *K9out = Ku << 9;
    }
  }
}

// ---------------------------------------------------------------------------
// Kernel D: 45M-element gumbel-sigmoid binarize with bits-space fast path.
// 4 elems/thread, ONE dwordx4 nt store -> dense wave stores.  Grid exactly
// BIN_N/1024 = 44032.  Output is 0 only if u > 1 - exp(-exp(pre+3));
// compare raw bits vs precomputed K9 (uniform scalar load).
// ---------------------------------------------------------------------------
__device__ inline float decide(float pre, uint32_t bits) {
  float u = jax_uniform(bits);
  float om = 1.0f - u;                 // exact for u >= 0.5 (Sterbenz)
  float e = -__logf(om);
  float gum = -__logf(e);              // e==0 -> +inf -> 1
  float z = pre + gum + 3.0f;
  return (z > 0.0f) ? 1.0f : 0.0f;
}

__global__ __launch_bounds__(256) void krnD(const float* __restrict__ P,
                                            const int* __restrict__ eidx,
                                            const uint32_t* __restrict__ K9p,
                                            float* __restrict__ out,
                                            uint32_t K2A, uint32_t K2B) {
  const uint32_t K9 = *K9p;                      // uniform (scalar) load

  uint32_t g = (blockIdx.x * 256u + threadIdx.x) * 4u;
  uint32_t b0 = jax_bits32(K2A, K2B, g + 0u);
  uint32_t b1 = jax_bits32(K2A, K2B, g + 1u);
  uint32_t b2 = jax_bits32(K2A, K2B, g + 2u);
  uint32_t b3 = jax_bits32(K2A, K2B, g + 3u);
  floatx4 r = {1.0f, 1.0f, 1.0f, 1.0f};
  uint32_t mx = max(max(b0, b1), max(b2, b3));
  if (mx >= K9) {                                // rare
    uint32_t row = g / (uint32_t)M_DIM;          // 4 elems share a row
    uint32_t m = g - row * (uint32_t)M_DIM;
    const float* pp = &P[(size_t)eidx[row] * M_DIM + m];
    if (b0 >= K9) r.x = decide(pp[0], b0);
    if (b1 >= K9) r.y = decide(pp[1], b1);
    if (b2 >= K9) r.z = decide(pp[2], b2);
    if (b3 >= K9) r.w = decide(pp[3], b3);
  }
  __builtin_nontemporal_store(r, (floatx4*)&out[g]);
}

// ---------------------------------------------------------------------------
extern "C" void kernel_launch(void* const* d_in, const int* in_sizes, int n_in,
                              void* d_out, int out_size, void* d_ws, size_t ws_size,
                              hipStream_t stream) {
  const float* x    = (const float*)d_in[0];
  const float* rnn  = (const float*)d_in[1];
  const float* Wr   = (const float*)d_in[2];
  const float* Wd   = (const float*)d_in[3];
  const float* lnw  = (const float*)d_in[4];
  const float* lnb  = (const float*)d_in[5];
  float* out = (float*)d_out;

  // k1, k2 = split(key(42)) -- foldlike split (verified prior session)
  uint32_t K1A, K1B, K2A, K2B;
  tf2x32(0u, 42u, 0u, 0u, K1A, K1B);
  tf2x32(0u, 42u, 0u, 1u, K2A, K2B);

  // workspace (ws): small buffers only.  Logit partials (33.5 MB) live in
  // the binary region of d_out, which krnD fully overwrites afterwards.
  char* ws = (char*)d_ws;
  int*      eidx    = (int*)ws;                       // 16 KB
  float*    P       = (float*)(ws + 65536);           // 2.82 MB (16B aligned)
  float*    pminLoc = (float*)(ws + 2990080);         // 688 B
  uint32_t* K9u     = (uint32_t*)(ws + 2991104);      // 4 B

  float* part = out;                      // scratch inside binary region
  float* router_out = out + (size_t)BIN_N;

  krnA<<<dim3(16, KSPLIT), 256, 0, stream>>>(x, Wr, part);
  krnC2<<<C2BLKS, 256, 0, stream>>>(rnn, lnw, lnb, Wd, P, pminLoc);
  krnB<<<1024, 256, 0, stream>>>(part, router_out, eidx, pminLoc, K9u, K1A, K1B);
  krnD<<<44032, 256, 0, stream>>>(P, eidx, K9u, out, K2A, K2B);
}

// Round 2
// 325.761 us; speedup vs baseline: 1.0267x; 1.0085x over previous
//
#include <hip/hip_runtime.h>
#include <hip/hip_bf16.h>
#include <stdint.h>

typedef float floatx4 __attribute__((ext_vector_type(4)));

// ---------------------------------------------------------------------------
// Threefry-2x32 (JAX-exact): 20 rounds, key injection every 4.
// ---------------------------------------------------------------------------
__host__ __device__ inline uint32_t rotl32(uint32_t x, int r) {
#ifdef __HIP_DEVICE_COMPILE__
  return __builtin_amdgcn_alignbit(x, x, 32 - r);
#else
  return (x << r) | (x >> (32 - r));
#endif
}

__host__ __device__ inline void tf2x32(uint32_t k0, uint32_t k1,
                                       uint32_t x0, uint32_t x1,
                                       uint32_t& o0, uint32_t& o1) {
  const uint32_t k2 = k0 ^ k1 ^ 0x1BD11BDAu;
  x0 += k0; x1 += k1;
#define TFR(r) { x0 += x1; x1 = rotl32(x1, r); x1 ^= x0; }
  TFR(13) TFR(15) TFR(26) TFR(6)
  x0 += k1; x1 += k2 + 1u;
  TFR(17) TFR(29) TFR(16) TFR(24)
  x0 += k2; x1 += k0 + 2u;
  TFR(13) TFR(15) TFR(26) TFR(6)
  x0 += k0; x1 += k1 + 3u;
  TFR(17) TFR(29) TFR(16) TFR(24)
  x0 += k1; x1 += k2 + 4u;
  TFR(13) TFR(15) TFR(26) TFR(6)
  x0 += k2; x1 += k0 + 5u;
#undef TFR
  o0 = x0; o1 = x1;
}

// Partitionable-mode 32-bit random bits, counts (0, i), bits = o0 ^ o1.
// [verified bit-exact vs np ref in prior session rounds 3-8]
__device__ inline uint32_t jax_bits32(uint32_t kA, uint32_t kB, uint32_t i) {
  uint32_t o0, o1;
  tf2x32(kA, kB, 0u, i, o0, o1);
  return o0 ^ o1;
}

__device__ inline float jax_uniform(uint32_t bits) {
  return __uint_as_float((bits >> 9) | 0x3f800000u) - 1.0f;
}

#define D_DIM   4096
#define E_DIM   64
#define EMB     128
#define M_DIM   11008
#define NROWS   4096          // B*S
#define BIN_N   45088768      // NROWS*M_DIM
#define KSPLIT  32            // k-splits in krnA (each 128 wide)
#define CK      32            // staged k-chunk
#define XSTR    284           // verified: 256 rows + quad-spread padding
#define WSTR    68            // verified
#define C2BLKS  172           // M_DIM / 64

// quad-spread address within a k-line: fragment f = v>>3 at f*8 + (f>>2)*4 so
// the 8 fragments of one wave's b128 read start in 8 distinct bank quads.
__device__ inline int qspread(int v) { return v + ((v >> 5) << 2); }

// ---------------------------------------------------------------------------
// Kernel A: logits partials, transposed-LDS outer-product fp32 GEMM.
// Grid (16 row-blocks, 32 k-splits) x 256 thr.  Block: 256 rows x 64 experts
// over 128 K.
// NEW mapping (R2): wave w owns experts [w*16, w*16+16); lane l owns rows
// [4l, 4l+4).  The 16-expert fragment is WAVE-UNIFORM -> 4 broadcast
// ds_read_b128 (cheap) + 1 distinct ds_read_b128 per k, vs 4 distinct before.
// Cuts LDS-pipe demand ~48 -> ~28 cyc per wave-k (was the bottleneck).
// Same FMA order as before -> bit-identical partials.
// ---------------------------------------------------------------------------
__global__ __launch_bounds__(256) void krnA(const float* __restrict__ x,
                                            const float* __restrict__ Wr,
                                            float* __restrict__ part) {
  __shared__ __align__(16) float xsT[CK * XSTR];   // 35.5 KB
  __shared__ __align__(16) float wsT[CK * WSTR];   // 8.5 KB
  const int rb = blockIdx.x, ks = blockIdx.y, t = threadIdx.x;
  const int rbase = rb * 256, kbase0 = ks * 128;
  const int w = t >> 6, l = t & 63;
  const int xoff = 4 * l + ((l >> 3) << 2);        // qspread(4*l)
  const int woff = (w * 16) + ((w * 16 >> 5) << 2);// qspread(w*16): 0,16,36,52
  float acc[4][16] = {};

  for (int c = 0; c < 4; ++c) {
    const int kbase = kbase0 + c * CK;
    // stage x: 256 rows x 32 k (8 float4 / thread, coalesced)
#pragma unroll
    for (int it = 0; it < 8; ++it) {
      int idx = t + it * 256;
      int row = idx >> 3, kq = idx & 7;
      float4 v = *(const float4*)&x[(size_t)(rbase + row) * D_DIM + kbase + kq * 4];
      int adr = qspread(row);
      xsT[(kq * 4 + 0) * XSTR + adr] = v.x;
      xsT[(kq * 4 + 1) * XSTR + adr] = v.y;
      xsT[(kq * 4 + 2) * XSTR + adr] = v.z;
      xsT[(kq * 4 + 3) * XSTR + adr] = v.w;
    }
    // stage Wr: 64 experts x 32 k (2 float4 / thread)
#pragma unroll
    for (int it = 0; it < 2; ++it) {
      int idx = t + it * 256;
      int e = idx >> 3, kq = idx & 7;
      float4 v = *(const float4*)&Wr[(size_t)e * D_DIM + kbase + kq * 4];
      int adr = qspread(e);
      wsT[(kq * 4 + 0) * WSTR + adr] = v.x;
      wsT[(kq * 4 + 1) * WSTR + adr] = v.y;
      wsT[(kq * 4 + 2) * WSTR + adr] = v.z;
      wsT[(kq * 4 + 3) * WSTR + adr] = v.w;
    }
    __syncthreads();
#pragma unroll
    for (int k = 0; k < CK; ++k) {
      const float* xp = &xsT[k * XSTR + xoff];
      const float* wp = &wsT[k * WSTR + woff];
      floatx4 xa = *(const floatx4*)xp;            // rows 4l..4l+3 (distinct)
      floatx4 w0 = *(const floatx4*)(wp);          // experts (wave-uniform,
      floatx4 w1 = *(const floatx4*)(wp + 4);      //  broadcast reads)
      floatx4 w2 = *(const floatx4*)(wp + 8);
      floatx4 w3 = *(const floatx4*)(wp + 12);
#pragma unroll
      for (int r = 0; r < 4; ++r) {
#pragma unroll
        for (int e = 0; e < 4; ++e) {
          acc[r][e]      += xa[r] * w0[e];
          acc[r][e + 4]  += xa[r] * w1[e];
          acc[r][e + 8]  += xa[r] * w2[e];
          acc[r][e + 12] += xa[r] * w3[e];
        }
      }
    }
    __syncthreads();
  }
  // write partials: part[row][ks][e]; wave w writes expert quarter w*16..+16.
  // The block's 4 waves assemble the full contiguous 256 B per row in L2.
#pragma unroll
  for (int r = 0; r < 4; ++r) {
    float* pp = part + ((size_t)(rbase + 4 * l + r) * KSPLIT + ks) * E_DIM + w * 16;
    *(float4*)(pp + 0)  = make_float4(acc[r][0],  acc[r][1],  acc[r][2],  acc[r][3]);
    *(float4*)(pp + 4)  = make_float4(acc[r][4],  acc[r][5],  acc[r][6],  acc[r][7]);
    *(float4*)(pp + 8)  = make_float4(acc[r][8],  acc[r][9],  acc[r][10], acc[r][11]);
    *(float4*)(pp + 12) = make_float4(acc[r][12], acc[r][13], acc[r][14], acc[r][15]);
  }
}

// ---------------------------------------------------------------------------
// Kernel C2 (fused): LN+GELU of rnn_state computed in-LDS, then
// P[e][m] = sum_c H[e][c]*Wd[m][c], plus per-block min -> pminLoc[blk].
// ---------------------------------------------------------------------------
__global__ __launch_bounds__(256) void krnC2(const float* __restrict__ rnn,
                                             const float* __restrict__ lnw,
                                             const float* __restrict__ lnb,
                                             const float* __restrict__ Wd,
                                             float* __restrict__ P,
                                             float* __restrict__ pminLoc) {
  __shared__ float4 hs[64][33];    // +1 pad: conflict-free b128 writes
  __shared__ float rmin[4];
  const int t = threadIdx.x;
  // --- LN + GELU: thread t handles 32 elems of row r = t>>2 (q = t&3) ---
  {
    const int r = t >> 2, q = t & 3;
    const float4* rp = (const float4*)(rnn + r * EMB) + q * 8;
    float4 v[8];
    float s = 0.0f;
#pragma unroll
    for (int j = 0; j < 8; ++j) {
      v[j] = rp[j];
      s += v[j].x + v[j].y + v[j].z + v[j].w;
    }
    s += __shfl_xor(s, 1); s += __shfl_xor(s, 2);       // 4-lane group = row
    const float mu = s * (1.0f / 128.0f);
    float qs = 0.0f;
#pragma unroll
    for (int j = 0; j < 8; ++j) {
      float dx = v[j].x - mu, dy = v[j].y - mu, dz = v[j].z - mu, dw = v[j].w - mu;
      qs += dx * dx + dy * dy + dz * dz + dw * dw;
    }
    qs += __shfl_xor(qs, 1); qs += __shfl_xor(qs, 2);
    const float rs = rsqrtf(qs * (1.0f / 128.0f) + 1e-5f);
    const float4* wp = (const float4*)lnw + q * 8;
    const float4* bp = (const float4*)lnb + q * 8;
#pragma unroll
    for (int j = 0; j < 8; ++j) {
      float4 w = wp[j], b = bp[j], g;
      float h;
      h = (v[j].x - mu) * rs * w.x + b.x;
      g.x = 0.5f * h * (1.0f + erff(h * 0.70710678118654752f));
      h = (v[j].y - mu) * rs * w.y + b.y;
      g.y = 0.5f * h * (1.0f + erff(h * 0.70710678118654752f));
      h = (v[j].z - mu) * rs * w.z + b.z;
      g.z = 0.5f * h * (1.0f + erff(h * 0.70710678118654752f));
      h = (v[j].w - mu) * rs * w.w + b.w;
      g.w = 0.5f * h * (1.0f + erff(h * 0.70710678118654752f));
      hs[r][q * 8 + j] = g;
    }
  }
  __syncthreads();
  // --- GEMM ---
  const int wv = t >> 6, lane = t & 63;
  const int m = blockIdx.x * 64 + lane;
  const float4* wd4 = (const float4*)(Wd + (size_t)m * EMB);
  float acc[16] = {};
  for (int c4 = 0; c4 < 32; ++c4) {
    float4 w = wd4[c4];
#pragma unroll
    for (int e = 0; e < 16; ++e) {
      float4 h = hs[wv * 16 + e][c4];
      acc[e] += w.x * h.x + w.y * h.y + w.z * h.z + w.w * h.w;
    }
  }
  float mn = acc[0];
#pragma unroll
  for (int e = 0; e < 16; ++e) {
    P[(size_t)(wv * 16 + e) * M_DIM + m] = acc[e];
    mn = fminf(mn, acc[e]);
  }
#pragma unroll
  for (int off = 32; off >= 1; off >>= 1)
    mn = fminf(mn, __shfl_xor(mn, off));
  if (lane == 0) rmin[wv] = mn;
  __syncthreads();
  if (t == 0)
    pminLoc[blockIdx.x] = fminf(fminf(rmin[0], rmin[1]), fminf(rmin[2], rmin[3]));
}

// ---------------------------------------------------------------------------
// Kernel B: reduce 32 partial slices (contiguous 8 KB per row), add gumbel
// (k1), argmax over 64, write router one-hot + expert index.  Block 0 also
// folds pminLoc -> K9 (bits-space threshold) once for krnD.
// ---------------------------------------------------------------------------
__global__ __launch_bounds__(256) void krnB(const float* __restrict__ part,
                                            float* __restrict__ router_out,
                                            int* __restrict__ eidx,
                                            const float* __restrict__ pminLoc,
                                            uint32_t* __restrict__ K9out,
                                            uint32_t K1A, uint32_t K1B) {
  __shared__ float red[4];
  const int t = threadIdx.x;
  const int wv = t >> 6, lane = t & 63;
  const int row = blockIdx.x * 4 + wv;
  float lg = 0.0f;
#pragma unroll
  for (int s = 0; s < KSPLIT; ++s)
    lg += part[((size_t)row * KSPLIT + s) * E_DIM + lane];

  uint32_t jf = (uint32_t)row * 64u + (uint32_t)lane;
  uint32_t bits = jax_bits32(K1A, K1B, jf);
  float u = jax_uniform(bits);
  float inner = -logf(u + 1e-20f);       // precise log: argmax sensitivity
  float g = -logf(inner + 1e-20f);
  float w = (lg + g) * 2.5f;

  float m = w;
#pragma unroll
  for (int off = 32; off >= 1; off >>= 1) m = fmaxf(m, __shfl_xor(m, off));
  unsigned long long msk = __ballot(w == m);
  int arg = __ffsll(msk) - 1;            // first max index == jnp.argmax
  router_out[(size_t)row * E_DIM + lane] = (lane == arg) ? 1.0f : 0.0f;
  if (lane == 0) eidx[row] = arg;

  if (blockIdx.x == 0) {                 // K9 precompute (once per launch)
    float v = (t < C2BLKS) ? pminLoc[t] : 3.0e38f;
#pragma unroll
    for (int off = 32; off >= 1; off >>= 1) v = fminf(v, __shfl_xor(v, off));
    if (lane == 0) red[wv] = v;
    __syncthreads();
    if (t == 0) {
      float pmin = fminf(fminf(red[0], red[1]), fminf(red[2], red[3]));
      float tt = pmin + 2.95f;                       // 0.05 safety slack
      float delta = __expf(-__expf(tt));
      delta = fminf(fmaxf(delta, 1.2e-7f), 0.5f);    // NaN-safe, Ku < 2^23
      uint32_t Ku = (uint32_t)((1.0f - delta) * 8388608.0f);
      *K9out = Ku << 9;
    }
  }
}

// ---------------------------------------------------------------------------
// Kernel D: 45M-element gumbel-sigmoid binarize with bits-space fast path.
// 4 elems/thread, ONE dwordx4 nt store -> dense wave stores.  Grid exactly
// BIN_N/1024 = 44032.  Output is 0 only if u > 1 - exp(-exp(pre+3));
// compare raw bits vs precomputed K9 (uniform scalar load).
// ---------------------------------------------------------------------------
__device__ inline float decide(float pre, uint32_t bits) {
  float u = jax_uniform(bits);
  float om = 1.0f - u;                 // exact for u >= 0.5 (Sterbenz)
  float e = -__logf(om);
  float gum = -__logf(e);              // e==0 -> +inf -> 1
  float z = pre + gum + 3.0f;
  return (z > 0.0f) ? 1.0f : 0.0f;
}

__global__ __launch_bounds__(256) void krnD(const float* __restrict__ P,
                                            const int* __restrict__ eidx,
                                            const uint32_t* __restrict__ K9p,
                                            float* __restrict__ out,
                                            uint32_t K2A, uint32_t K2B) {
  const uint32_t K9 = *K9p;                      // uniform (scalar) load

  uint32_t g = (blockIdx.x * 256u + threadIdx.x) * 4u;
  uint32_t b0 = jax_bits32(K2A, K2B, g + 0u);
  uint32_t b1 = jax_bits32(K2A, K2B, g + 1u);
  uint32_t b2 = jax_bits32(K2A, K2B, g + 2u);
  uint32_t b3 = jax_bits32(K2A, K2B, g + 3u);
  floatx4 r = {1.0f, 1.0f, 1.0f, 1.0f};
  uint32_t mx = max(max(b0, b1), max(b2, b3));
  if (mx >= K9) {                                // rare
    uint32_t row = g / (uint32_t)M_DIM;          // 4 elems share a row
    uint32_t m = g - row * (uint32_t)M_DIM;
    const float* pp = &P[(size_t)eidx[row] * M_DIM + m];
    if (b0 >= K9) r.x = decide(pp[0], b0);
    if (b1 >= K9) r.y = decide(pp[1], b1);
    if (b2 >= K9) r.z = decide(pp[2], b2);
    if (b3 >= K9) r.w = decide(pp[3], b3);
  }
  __builtin_nontemporal_store(r, (floatx4*)&out[g]);
}

// ---------------------------------------------------------------------------
extern "C" void kernel_launch(void* const* d_in, const int* in_sizes, int n_in,
                              void* d_out, int out_size, void* d_ws, size_t ws_size,
                              hipStream_t stream) {
  const float* x    = (const float*)d_in[0];
  const float* rnn  = (const float*)d_in[1];
  const float* Wr   = (const float*)d_in[2];
  const float* Wd   = (const float*)d_in[3];
  const float* lnw  = (const float*)d_in[4];
  const float* lnb  = (const float*)d_in[5];
  float* out = (float*)d_out;

  // k1, k2 = split(key(42)) -- foldlike split (verified prior session)
  uint32_t K1A, K1B, K2A, K2B;
  tf2x32(0u, 42u, 0u, 0u, K1A, K1B);
  tf2x32(0u, 42u, 0u, 1u, K2A, K2B);

  // workspace (ws): small buffers only.  Logit partials (33.5 MB) live in
  // the binary region of d_out, which krnD fully overwrites afterwards.
  char* ws = (char*)d_ws;
  int*      eidx    = (int*)ws;                       // 16 KB
  float*    P       = (float*)(ws + 65536);           // 2.82 MB (16B aligned)
  float*    pminLoc = (float*)(ws + 2990080);         // 688 B
  uint32_t* K9u     = (uint32_t*)(ws + 2991104);      // 4 B

  float* part = out;                      // scratch inside binary region
  float* router_out = out + (size_t)BIN_N;

  krnA<<<dim3(16, KSPLIT), 256, 0, stream>>>(x, Wr, part);
  krnC2<<<C2BLKS, 256, 0, stream>>>(rnn, lnw, lnb, Wd, P, pminLoc);
  krnB<<<1024, 256, 0, stream>>>(part, router_out, eidx, pminLoc, K9u, K1A, K1B);
  krnD<<<44032, 256, 0, stream>>>(P, eidx, K9u, out, K2A, K2B);
}

// Round 3
// 321.062 us; speedup vs baseline: 1.0418x; 1.0146x over previous
//
#include <hip/hip_runtime.h>
#include <hip/hip_bf16.h>
#include <stdint.h>

typedef float floatx4 __attribute__((ext_vector_type(4)));

// ---------------------------------------------------------------------------
// Threefry-2x32 (JAX-exact): 20 rounds, key injection every 4.
// ---------------------------------------------------------------------------
__host__ __device__ inline uint32_t rotl32(uint32_t x, int r) {
#ifdef __HIP_DEVICE_COMPILE__
  return __builtin_amdgcn_alignbit(x, x, 32 - r);
#else
  return (x << r) | (x >> (32 - r));
#endif
}

__host__ __device__ inline void tf2x32(uint32_t k0, uint32_t k1,
                                       uint32_t x0, uint32_t x1,
                                       uint32_t& o0, uint32_t& o1) {
  const uint32_t k2 = k0 ^ k1 ^ 0x1BD11BDAu;
  x0 += k0; x1 += k1;
#define TFR(r) { x0 += x1; x1 = rotl32(x1, r); x1 ^= x0; }
  TFR(13) TFR(15) TFR(26) TFR(6)
  x0 += k1; x1 += k2 + 1u;
  TFR(17) TFR(29) TFR(16) TFR(24)
  x0 += k2; x1 += k0 + 2u;
  TFR(13) TFR(15) TFR(26) TFR(6)
  x0 += k0; x1 += k1 + 3u;
  TFR(17) TFR(29) TFR(16) TFR(24)
  x0 += k1; x1 += k2 + 4u;
  TFR(13) TFR(15) TFR(26) TFR(6)
  x0 += k2; x1 += k0 + 5u;
#undef TFR
  o0 = x0; o1 = x1;
}

// Partitionable-mode 32-bit random bits, counts (0, i), bits = o0 ^ o1.
// [verified bit-exact vs np ref in prior session rounds 3-8]
__device__ inline uint32_t jax_bits32(uint32_t kA, uint32_t kB, uint32_t i) {
  uint32_t o0, o1;
  tf2x32(kA, kB, 0u, i, o0, o1);
  return o0 ^ o1;
}

__device__ inline float jax_uniform(uint32_t bits) {
  return __uint_as_float((bits >> 9) | 0x3f800000u) - 1.0f;
}

#define D_DIM   4096
#define E_DIM   64
#define EMB     128
#define M_DIM   11008
#define NROWS   4096          // B*S
#define BIN_N   45088768      // NROWS*M_DIM
#define KSPLIT  32            // k-splits (PINNED: matches XLA 32x128 sum order)
#define CK      32            // staged k-chunk
#define XSTR    284           // verified: 256 rows + quad-spread padding
#define WSTR    68            // verified
#define C2BLKS  172           // M_DIM / 64
#define TSTR    67            // epilogue transpose stride (bank-spread)

// quad-spread address within a k-line: fragment f = v>>3 at f*8 + (f>>2)*4 so
// the 8 fragments of one wave's b128 read start in 8 distinct bank quads.
__device__ inline int qspread(int v) { return v + ((v >> 5) << 2); }

// ---------------------------------------------------------------------------
// Kernel A+C2 merged (one dispatch).  Blocks [0, C2BLKS): the small decode
// GEMM (LN+GELU in-LDS, P + per-block min).  Blocks [C2BLKS, C2BLKS+512):
// logits partials GEMM.  Shared-memory arena overlaid per branch.
// ---------------------------------------------------------------------------
__global__ __launch_bounds__(256) void krnAC2(const float* __restrict__ x,
                                              const float* __restrict__ Wr,
                                              float* __restrict__ part,
                                              const float* __restrict__ rnn,
                                              const float* __restrict__ lnw,
                                              const float* __restrict__ lnb,
                                              const float* __restrict__ Wd,
                                              float* __restrict__ P,
                                              float* __restrict__ pminLoc) {
  __shared__ __align__(16) float smem[CK * XSTR + CK * WSTR + 4];  // 45 KB
  const int t = threadIdx.x;

  if (blockIdx.x < C2BLKS) {
    // ----------------------- C2 branch (unchanged math) --------------------
    float4 (*hs)[33] = (float4(*)[33])smem;          // 33.8 KB
    float* rmin = smem + 8448;                       // 4 floats
    {
      const int r = t >> 2, q = t & 3;
      const float4* rp = (const float4*)(rnn + r * EMB) + q * 8;
      float4 v[8];
      float s = 0.0f;
#pragma unroll
      for (int j = 0; j < 8; ++j) {
        v[j] = rp[j];
        s += v[j].x + v[j].y + v[j].z + v[j].w;
      }
      s += __shfl_xor(s, 1); s += __shfl_xor(s, 2);   // 4-lane group = row
      const float mu = s * (1.0f / 128.0f);
      float qs = 0.0f;
#pragma unroll
      for (int j = 0; j < 8; ++j) {
        float dx = v[j].x - mu, dy = v[j].y - mu, dz = v[j].z - mu, dw = v[j].w - mu;
        qs += dx * dx + dy * dy + dz * dz + dw * dw;
      }
      qs += __shfl_xor(qs, 1); qs += __shfl_xor(qs, 2);
      const float rs = rsqrtf(qs * (1.0f / 128.0f) + 1e-5f);
      const float4* wp = (const float4*)lnw + q * 8;
      const float4* bp = (const float4*)lnb + q * 8;
#pragma unroll
      for (int j = 0; j < 8; ++j) {
        float4 w = wp[j], b = bp[j], g;
        float h;
        h = (v[j].x - mu) * rs * w.x + b.x;
        g.x = 0.5f * h * (1.0f + erff(h * 0.70710678118654752f));
        h = (v[j].y - mu) * rs * w.y + b.y;
        g.y = 0.5f * h * (1.0f + erff(h * 0.70710678118654752f));
        h = (v[j].z - mu) * rs * w.z + b.z;
        g.z = 0.5f * h * (1.0f + erff(h * 0.70710678118654752f));
        h = (v[j].w - mu) * rs * w.w + b.w;
        g.w = 0.5f * h * (1.0f + erff(h * 0.70710678118654752f));
        hs[r][q * 8 + j] = g;
      }
    }
    __syncthreads();
    const int wv = t >> 6, lane = t & 63;
    const int m = blockIdx.x * 64 + lane;
    const float4* wd4 = (const float4*)(Wd + (size_t)m * EMB);
    float acc[16] = {};
    for (int c4 = 0; c4 < 32; ++c4) {
      float4 w = wd4[c4];
#pragma unroll
      for (int e = 0; e < 16; ++e) {
        float4 h = hs[wv * 16 + e][c4];
        acc[e] += w.x * h.x + w.y * h.y + w.z * h.z + w.w * h.w;
      }
    }
    float mn = acc[0];
#pragma unroll
    for (int e = 0; e < 16; ++e) {
      P[(size_t)(wv * 16 + e) * M_DIM + m] = acc[e];
      mn = fminf(mn, acc[e]);
    }
#pragma unroll
    for (int off = 32; off >= 1; off >>= 1)
      mn = fminf(mn, __shfl_xor(mn, off));
    if (lane == 0) rmin[wv] = mn;
    __syncthreads();
    if (t == 0)
      pminLoc[blockIdx.x] = fminf(fminf(rmin[0], rmin[1]), fminf(rmin[2], rmin[3]));
    return;
  }

  // ------------------------- A branch (logits GEMM) ------------------------
  float* xsT = smem;                 // CK*XSTR floats (36.3 KB)
  float* wsT = smem + CK * XSTR;     // CK*WSTR floats (8.7 KB)
  const int flat = blockIdx.x - C2BLKS;
  const int rb = flat & 15, ks = flat >> 4;
  const int rbase = rb * 256, kbase0 = ks * 128;
  const int w = t >> 6, l = t & 63;
  const int xoff = 4 * l + ((l >> 3) << 2);         // qspread(4*l)
  const int woff = (w * 16) + ((w * 16 >> 5) << 2); // qspread(w*16)
  float acc[4][16] = {};

  for (int c = 0; c < 4; ++c) {
    const int kbase = kbase0 + c * CK;
    // stage x: 256 rows x 32 k (8 float4 / thread, coalesced)
#pragma unroll
    for (int it = 0; it < 8; ++it) {
      int idx = t + it * 256;
      int row = idx >> 3, kq = idx & 7;
      float4 v = *(const float4*)&x[(size_t)(rbase + row) * D_DIM + kbase + kq * 4];
      int adr = qspread(row);
      xsT[(kq * 4 + 0) * XSTR + adr] = v.x;
      xsT[(kq * 4 + 1) * XSTR + adr] = v.y;
      xsT[(kq * 4 + 2) * XSTR + adr] = v.z;
      xsT[(kq * 4 + 3) * XSTR + adr] = v.w;
    }
    // stage Wr: 64 experts x 32 k (2 float4 / thread)
#pragma unroll
    for (int it = 0; it < 2; ++it) {
      int idx = t + it * 256;
      int e = idx >> 3, kq = idx & 7;
      float4 v = *(const float4*)&Wr[(size_t)e * D_DIM + kbase + kq * 4];
      int adr = qspread(e);
      wsT[(kq * 4 + 0) * WSTR + adr] = v.x;
      wsT[(kq * 4 + 1) * WSTR + adr] = v.y;
      wsT[(kq * 4 + 2) * WSTR + adr] = v.z;
      wsT[(kq * 4 + 3) * WSTR + adr] = v.w;
    }
    __syncthreads();
#pragma unroll
    for (int k = 0; k < CK; ++k) {
      const float* xp = &xsT[k * XSTR + xoff];
      const float* wp = &wsT[k * WSTR + woff];
      floatx4 xa = *(const floatx4*)xp;            // rows 4l..4l+3 (distinct)
      floatx4 w0 = *(const floatx4*)(wp);          // experts (wave-uniform,
      floatx4 w1 = *(const floatx4*)(wp + 4);      //  broadcast reads)
      floatx4 w2 = *(const floatx4*)(wp + 8);
      floatx4 w3 = *(const floatx4*)(wp + 12);
#pragma unroll
      for (int r = 0; r < 4; ++r) {
#pragma unroll
        for (int e = 0; e < 4; ++e) {
          acc[r][e]      += xa[r] * w0[e];
          acc[r][e + 4]  += xa[r] * w1[e];
          acc[r][e + 8]  += xa[r] * w2[e];
          acc[r][e + 12] += xa[r] * w3[e];
        }
      }
    }
    __syncthreads();
  }

  // --- epilogue: LDS-transpose so part stores are row-coalesced ---
  // Two 128-row chunks through xsT (reused; 128*TSTR = 8576 <= 9088 floats).
  // Write-side: lanes owning this chunk's rows deposit acc at [lrow][e];
  // read-side: 16 lanes span a row's 64 experts -> per store-inst 4 rows x
  // 4 lines = 16 txns (was 64).  Values/layout identical -> bit-exact.
  float* tr = xsT;
  for (int half = 0; half < 2; ++half) {
    __syncthreads();
    if ((l >> 5) == half) {
      const int lr = l & 31;                       // rows: half*128 + 4*lr ..
#pragma unroll
      for (int r = 0; r < 4; ++r) {
        float* dst = tr + (lr * 4 + r) * TSTR + w * 16;
        *(float4*)(dst + 0)  = make_float4(acc[r][0],  acc[r][1],  acc[r][2],  acc[r][3]);
        *(float4*)(dst + 4)  = make_float4(acc[r][4],  acc[r][5],  acc[r][6],  acc[r][7]);
        *(float4*)(dst + 8)  = make_float4(acc[r][8],  acc[r][9],  acc[r][10], acc[r][11]);
        *(float4*)(dst + 12) = make_float4(acc[r][12], acc[r][13], acc[r][14], acc[r][15]);
      }
    }
    __syncthreads();
#pragma unroll
    for (int it = 0; it < 8; ++it) {
      const int lrow = (t >> 4) + it * 16;         // 0..127
      const int grow = rbase + half * 128 + lrow;  // global row
      float4 v = *(const float4*)(tr + lrow * TSTR + (t & 15) * 4);
      *(float4*)(part + ((size_t)grow * KSPLIT + ks) * E_DIM + (t & 15) * 4) = v;
    }
  }
}

// ---------------------------------------------------------------------------
// Kernel B: reduce 32 partial slices (contiguous 8 KB per row), add gumbel
// (k1), argmax over 64, write router one-hot + expert index.  Block 0 also
// folds pminLoc -> K9 (bits-space threshold) once for krnD.
// ---------------------------------------------------------------------------
__global__ __launch_bounds__(256) void krnB(const float* __restrict__ part,
                                            float* __restrict__ router_out,
                                            int* __restrict__ eidx,
                                            const float* __restrict__ pminLoc,
                                            uint32_t* __restrict__ K9out,
                                            uint32_t K1A, uint32_t K1B) {
  __shared__ float red[4];
  const int t = threadIdx.x;
  const int wv = t >> 6, lane = t & 63;
  const int row = blockIdx.x * 4 + wv;
  float lg = 0.0f;
#pragma unroll
  for (int s = 0; s < KSPLIT; ++s)
    lg += part[((size_t)row * KSPLIT + s) * E_DIM + lane];

  uint32_t jf = (uint32_t)row * 64u + (uint32_t)lane;
  uint32_t bits = jax_bits32(K1A, K1B, jf);
  float u = jax_uniform(bits);
  float inner = -logf(u + 1e-20f);       // precise log: argmax sensitivity
  float g = -logf(inner + 1e-20f);
  float w = (lg + g) * 2.5f;

  float m = w;
#pragma unroll
  for (int off = 32; off >= 1; off >>= 1) m = fmaxf(m, __shfl_xor(m, off));
  unsigned long long msk = __ballot(w == m);
  int arg = __ffsll(msk) - 1;            // first max index == jnp.argmax
  router_out[(size_t)row * E_DIM + lane] = (lane == arg) ? 1.0f : 0.0f;
  if (lane == 0) eidx[row] = arg;

  if (blockIdx.x == 0) {                 // K9 precompute (once per launch)
    float v = (t < C2BLKS) ? pminLoc[t] : 3.0e38f;
#pragma unroll
    for (int off = 32; off >= 1; off >>= 1) v = fminf(v, __shfl_xor(v, off));
    if (lane == 0) red[wv] = v;
    __syncthreads();
    if (t == 0) {
      float pmin = fminf(fminf(red[0], red[1]), fminf(red[2], red[3]));
      float tt = pmin + 2.95f;                       // 0.05 safety slack
      float delta = __expf(-__expf(tt));
      delta = fminf(fmaxf(delta, 1.2e-7f), 0.5f);    // NaN-safe, Ku < 2^23
      uint32_t Ku = (uint32_t)((1.0f - delta) * 8388608.0f);
      *K9out = Ku << 9;
    }
  }
}

// ---------------------------------------------------------------------------
// Kernel D: 45M-element gumbel-sigmoid binarize with bits-space fast path.
// 4 elems/thread, ONE dwordx4 nt store -> dense wave stores.  Grid exactly
// BIN_N/1024 = 44032.  Output is 0 only if u > 1 - exp(-exp(pre+3));
// compare raw bits vs precomputed K9 (uniform scalar load).
// ---------------------------------------------------------------------------
__device__ inline float decide(float pre, uint32_t bits) {
  float u = jax_uniform(bits);
  float om = 1.0f - u;                 // exact for u >= 0.5 (Sterbenz)
  float e = -__logf(om);
  float gum = -__logf(e);              // e==0 -> +inf -> 1
  float z = pre + gum + 3.0f;
  return (z > 0.0f) ? 1.0f : 0.0f;
}

__global__ __launch_bounds__(256) void krnD(const float* __restrict__ P,
                                            const int* __restrict__ eidx,
                                            const uint32_t* __restrict__ K9p,
                                            float* __restrict__ out,
                                            uint32_t K2A, uint32_t K2B) {
  const uint32_t K9 = *K9p;                      // uniform (scalar) load

  uint32_t g = (blockIdx.x * 256u + threadIdx.x) * 4u;
  uint32_t b0 = jax_bits32(K2A, K2B, g + 0u);
  uint32_t b1 = jax_bits32(K2A, K2B, g + 1u);
  uint32_t b2 = jax_bits32(K2A, K2B, g + 2u);
  uint32_t b3 = jax_bits32(K2A, K2B, g + 3u);
  floatx4 r = {1.0f, 1.0f, 1.0f, 1.0f};
  uint32_t mx = max(max(b0, b1), max(b2, b3));
  if (mx >= K9) {                                // rare
    uint32_t row = g / (uint32_t)M_DIM;          // 4 elems share a row
    uint32_t m = g - row * (uint32_t)M_DIM;
    const float* pp = &P[(size_t)eidx[row] * M_DIM + m];
    if (b0 >= K9) r.x = decide(pp[0], b0);
    if (b1 >= K9) r.y = decide(pp[1], b1);
    if (b2 >= K9) r.z = decide(pp[2], b2);
    if (b3 >= K9) r.w = decide(pp[3], b3);
  }
  __builtin_nontemporal_store(r, (floatx4*)&out[g]);
}

// ---------------------------------------------------------------------------
extern "C" void kernel_launch(void* const* d_in, const int* in_sizes, int n_in,
                              void* d_out, int out_size, void* d_ws, size_t ws_size,
                              hipStream_t stream) {
  const float* x    = (const float*)d_in[0];
  const float* rnn  = (const float*)d_in[1];
  const float* Wr   = (const float*)d_in[2];
  const float* Wd   = (const float*)d_in[3];
  const float* lnw  = (const float*)d_in[4];
  const float* lnb  = (const float*)d_in[5];
  float* out = (float*)d_out;

  // k1, k2 = split(key(42)) -- foldlike split (verified prior session)
  uint32_t K1A, K1B, K2A, K2B;
  tf2x32(0u, 42u, 0u, 0u, K1A, K1B);
  tf2x32(0u, 42u, 0u, 1u, K2A, K2B);

  // workspace (ws): small buffers only.  Logit partials (33.5 MB) live in
  // the binary region of d_out, which krnD fully overwrites afterwards.
  char* ws = (char*)d_ws;
  int*      eidx    = (int*)ws;                       // 16 KB
  float*    P       = (float*)(ws + 65536);           // 2.82 MB (16B aligned)
  float*    pminLoc = (float*)(ws + 2990080);         // 688 B
  uint32_t* K9u     = (uint32_t*)(ws + 2991104);      // 4 B

  float* part = out;                      // scratch inside binary region
  float* router_out = out + (size_t)BIN_N;

  krnAC2<<<C2BLKS + 512, 256, 0, stream>>>(x, Wr, part, rnn, lnw, lnb, Wd, P, pminLoc);
  krnB<<<1024, 256, 0, stream>>>(part, router_out, eidx, pminLoc, K9u, K1A, K1B);
  krnD<<<44032, 256, 0, stream>>>(P, eidx, K9u, out, K2A, K2B);
}

// Round 4
// 316.740 us; speedup vs baseline: 1.0560x; 1.0136x over previous
//
#include <hip/hip_runtime.h>
#include <hip/hip_bf16.h>
#include <stdint.h>

typedef float floatx4 __attribute__((ext_vector_type(4)));

// ---------------------------------------------------------------------------
// Threefry-2x32 (JAX-exact): 20 rounds, key injection every 4.
// ---------------------------------------------------------------------------
__host__ __device__ inline uint32_t rotl32(uint32_t x, int r) {
#ifdef __HIP_DEVICE_COMPILE__
  return __builtin_amdgcn_alignbit(x, x, 32 - r);
#else
  return (x << r) | (x >> (32 - r));
#endif
}

__host__ __device__ inline void tf2x32(uint32_t k0, uint32_t k1,
                                       uint32_t x0, uint32_t x1,
                                       uint32_t& o0, uint32_t& o1) {
  const uint32_t k2 = k0 ^ k1 ^ 0x1BD11BDAu;
  x0 += k0; x1 += k1;
#define TFR(r) { x0 += x1; x1 = rotl32(x1, r); x1 ^= x0; }
  TFR(13) TFR(15) TFR(26) TFR(6)
  x0 += k1; x1 += k2 + 1u;
  TFR(17) TFR(29) TFR(16) TFR(24)
  x0 += k2; x1 += k0 + 2u;
  TFR(13) TFR(15) TFR(26) TFR(6)
  x0 += k0; x1 += k1 + 3u;
  TFR(17) TFR(29) TFR(16) TFR(24)
  x0 += k1; x1 += k2 + 4u;
  TFR(13) TFR(15) TFR(26) TFR(6)
  x0 += k2; x1 += k0 + 5u;
#undef TFR
  o0 = x0; o1 = x1;
}

// Partitionable-mode 32-bit random bits, counts (0, i), bits = o0 ^ o1.
// [verified bit-exact vs np ref in prior session rounds 3-8]
__device__ inline uint32_t jax_bits32(uint32_t kA, uint32_t kB, uint32_t i) {
  uint32_t o0, o1;
  tf2x32(kA, kB, 0u, i, o0, o1);
  return o0 ^ o1;
}

__device__ inline float jax_uniform(uint32_t bits) {
  return __uint_as_float((bits >> 9) | 0x3f800000u) - 1.0f;
}

#define D_DIM   4096
#define E_DIM   64
#define EMB     128
#define M_DIM   11008
#define NROWS   4096          // B*S
#define BIN_N   45088768      // NROWS*M_DIM
#define KSPLIT  32            // k-splits (PINNED: matches XLA 32x128 sum order)
#define CK      16            // staged k-chunk (was 32; halved for occupancy)
#define XSTR    284           // verified: 256 rows + quad-spread padding
#define WSTR    68            // verified
#define C2BLKS  172           // M_DIM / 64
#define TSTR    67            // epilogue transpose stride (bank-spread)
#define SMEMF   8452          // LDS floats: C2 branch dominates (33.8 KB)

// quad-spread address within a k-line: fragment f = v>>3 at f*8 + (f>>2)*4 so
// the 8 fragments of one wave's b128 read start in 8 distinct bank quads.
__device__ inline int qspread(int v) { return v + ((v >> 5) << 2); }

// ---------------------------------------------------------------------------
// Kernel A+C2 merged (one dispatch).  Blocks [0, C2BLKS): the small decode
// GEMM (LN+GELU in-LDS, P + per-block min).  Blocks [C2BLKS, C2BLKS+512):
// logits partials GEMM.  LDS arena 33.8 KB -> 4 blocks/CU (was 3 at 45 KB).
// ---------------------------------------------------------------------------
__global__ __launch_bounds__(256) void krnAC2(const float* __restrict__ x,
                                              const float* __restrict__ Wr,
                                              float* __restrict__ part,
                                              const float* __restrict__ rnn,
                                              const float* __restrict__ lnw,
                                              const float* __restrict__ lnb,
                                              const float* __restrict__ Wd,
                                              float* __restrict__ P,
                                              float* __restrict__ pminLoc) {
  __shared__ __align__(16) float smem[SMEMF];      // 33.8 KB
  const int t = threadIdx.x;

  if (blockIdx.x < C2BLKS) {
    // ----------------------- C2 branch (unchanged math) --------------------
    float4 (*hs)[33] = (float4(*)[33])smem;          // 33.8 KB
    float* rmin = smem + 8448;                       // 4 floats
    {
      const int r = t >> 2, q = t & 3;
      const float4* rp = (const float4*)(rnn + r * EMB) + q * 8;
      float4 v[8];
      float s = 0.0f;
#pragma unroll
      for (int j = 0; j < 8; ++j) {
        v[j] = rp[j];
        s += v[j].x + v[j].y + v[j].z + v[j].w;
      }
      s += __shfl_xor(s, 1); s += __shfl_xor(s, 2);   // 4-lane group = row
      const float mu = s * (1.0f / 128.0f);
      float qs = 0.0f;
#pragma unroll
      for (int j = 0; j < 8; ++j) {
        float dx = v[j].x - mu, dy = v[j].y - mu, dz = v[j].z - mu, dw = v[j].w - mu;
        qs += dx * dx + dy * dy + dz * dz + dw * dw;
      }
      qs += __shfl_xor(qs, 1); qs += __shfl_xor(qs, 2);
      const float rs = rsqrtf(qs * (1.0f / 128.0f) + 1e-5f);
      const float4* wp = (const float4*)lnw + q * 8;
      const float4* bp = (const float4*)lnb + q * 8;
#pragma unroll
      for (int j = 0; j < 8; ++j) {
        float4 w = wp[j], b = bp[j], g;
        float h;
        h = (v[j].x - mu) * rs * w.x + b.x;
        g.x = 0.5f * h * (1.0f + erff(h * 0.70710678118654752f));
        h = (v[j].y - mu) * rs * w.y + b.y;
        g.y = 0.5f * h * (1.0f + erff(h * 0.70710678118654752f));
        h = (v[j].z - mu) * rs * w.z + b.z;
        g.z = 0.5f * h * (1.0f + erff(h * 0.70710678118654752f));
        h = (v[j].w - mu) * rs * w.w + b.w;
        g.w = 0.5f * h * (1.0f + erff(h * 0.70710678118654752f));
        hs[r][q * 8 + j] = g;
      }
    }
    __syncthreads();
    const int wv = t >> 6, lane = t & 63;
    const int m = blockIdx.x * 64 + lane;
    const float4* wd4 = (const float4*)(Wd + (size_t)m * EMB);
    float acc[16] = {};
    for (int c4 = 0; c4 < 32; ++c4) {
      float4 w = wd4[c4];
#pragma unroll
      for (int e = 0; e < 16; ++e) {
        float4 h = hs[wv * 16 + e][c4];
        acc[e] += w.x * h.x + w.y * h.y + w.z * h.z + w.w * h.w;
      }
    }
    float mn = acc[0];
#pragma unroll
    for (int e = 0; e < 16; ++e) {
      P[(size_t)(wv * 16 + e) * M_DIM + m] = acc[e];
      mn = fminf(mn, acc[e]);
    }
#pragma unroll
    for (int off = 32; off >= 1; off >>= 1)
      mn = fminf(mn, __shfl_xor(mn, off));
    if (lane == 0) rmin[wv] = mn;
    __syncthreads();
    if (t == 0)
      pminLoc[blockIdx.x] = fminf(fminf(rmin[0], rmin[1]), fminf(rmin[2], rmin[3]));
    return;
  }

  // ------------------------- A branch (logits GEMM) ------------------------
  float* xsT = smem;                 // CK*XSTR floats (17.8 KB)
  float* wsT = smem + CK * XSTR;     // CK*WSTR floats (4.3 KB)
  const int flat = blockIdx.x - C2BLKS;
  const int rb = flat & 15, ks = flat >> 4;
  const int rbase = rb * 256, kbase0 = ks * 128;
  const int w = t >> 6, l = t & 63;
  const int xoff = 4 * l + ((l >> 3) << 2);         // qspread(4*l)
  const int woff = (w * 16) + ((w * 16 >> 5) << 2); // qspread(w*16)
  float acc[4][16] = {};

  for (int c = 0; c < 8; ++c) {                     // 8 chunks of 16 K
    const int kbase = kbase0 + c * CK;
    // stage x: 256 rows x 16 k (4 float4 / thread, coalesced)
#pragma unroll
    for (int it = 0; it < 4; ++it) {
      int idx = t + it * 256;
      int row = idx >> 2, kq = idx & 3;
      float4 v = *(const float4*)&x[(size_t)(rbase + row) * D_DIM + kbase + kq * 4];
      int adr = qspread(row);
      xsT[(kq * 4 + 0) * XSTR + adr] = v.x;
      xsT[(kq * 4 + 1) * XSTR + adr] = v.y;
      xsT[(kq * 4 + 2) * XSTR + adr] = v.z;
      xsT[(kq * 4 + 3) * XSTR + adr] = v.w;
    }
    // stage Wr: 64 experts x 16 k (1 float4 / thread)
    {
      int e = t >> 2, kq = t & 3;
      float4 v = *(const float4*)&Wr[(size_t)e * D_DIM + kbase + kq * 4];
      int adr = qspread(e);
      wsT[(kq * 4 + 0) * WSTR + adr] = v.x;
      wsT[(kq * 4 + 1) * WSTR + adr] = v.y;
      wsT[(kq * 4 + 2) * WSTR + adr] = v.z;
      wsT[(kq * 4 + 3) * WSTR + adr] = v.w;
    }
    __syncthreads();
#pragma unroll
    for (int k = 0; k < CK; ++k) {
      const float* xp = &xsT[k * XSTR + xoff];
      const float* wp = &wsT[k * WSTR + woff];
      floatx4 xa = *(const floatx4*)xp;            // rows 4l..4l+3 (distinct)
      floatx4 w0 = *(const floatx4*)(wp);          // experts (wave-uniform,
      floatx4 w1 = *(const floatx4*)(wp + 4);      //  broadcast reads)
      floatx4 w2 = *(const floatx4*)(wp + 8);
      floatx4 w3 = *(const floatx4*)(wp + 12);
#pragma unroll
      for (int r = 0; r < 4; ++r) {
#pragma unroll
        for (int e = 0; e < 4; ++e) {
          acc[r][e]      += xa[r] * w0[e];
          acc[r][e + 4]  += xa[r] * w1[e];
          acc[r][e + 8]  += xa[r] * w2[e];
          acc[r][e + 12] += xa[r] * w3[e];
        }
      }
    }
    __syncthreads();
  }

  // --- epilogue: LDS-transpose so part stores are row-coalesced ---
  // Four 64-row quarters through smem (64*TSTR = 4288 floats <= arena).
  // Write-side: lanes owning this quarter's rows deposit acc at [lrow][e];
  // read-side: 16 lanes span a row's 64 experts -> per store-inst 4 rows x
  // 4 lines = 16 txns.  Values/layout identical -> bit-exact.
  float* tr = smem;
  for (int qtr = 0; qtr < 4; ++qtr) {
    __syncthreads();
    if ((l >> 4) == qtr) {
      const int lr = l & 15;                       // rows: qtr*64 + 4*lr ..
#pragma unroll
      for (int r = 0; r < 4; ++r) {
        float* dst = tr + (lr * 4 + r) * TSTR + w * 16;
        *(float4*)(dst + 0)  = make_float4(acc[r][0],  acc[r][1],  acc[r][2],  acc[r][3]);
        *(float4*)(dst + 4)  = make_float4(acc[r][4],  acc[r][5],  acc[r][6],  acc[r][7]);
        *(float4*)(dst + 8)  = make_float4(acc[r][8],  acc[r][9],  acc[r][10], acc[r][11]);
        *(float4*)(dst + 12) = make_float4(acc[r][12], acc[r][13], acc[r][14], acc[r][15]);
      }
    }
    __syncthreads();
#pragma unroll
    for (int it = 0; it < 4; ++it) {
      const int lrow = (t >> 4) + it * 16;         // 0..63
      const int grow = rbase + qtr * 64 + lrow;    // global row
      float4 v = *(const float4*)(tr + lrow * TSTR + (t & 15) * 4);
      *(float4*)(part + ((size_t)grow * KSPLIT + ks) * E_DIM + (t & 15) * 4) = v;
    }
  }
}

// ---------------------------------------------------------------------------
// Kernel B: reduce 32 partial slices (contiguous 8 KB per row), add gumbel
// (k1), argmax over 64, write router one-hot + expert index.  Block 0 also
// folds pminLoc -> K9 (bits-space threshold) once for krnD.
// ---------------------------------------------------------------------------
__global__ __launch_bounds__(256) void krnB(const float* __restrict__ part,
                                            float* __restrict__ router_out,
                                            int* __restrict__ eidx,
                                            const float* __restrict__ pminLoc,
                                            uint32_t* __restrict__ K9out,
                                            uint32_t K1A, uint32_t K1B) {
  __shared__ float red[4];
  const int t = threadIdx.x;
  const int wv = t >> 6, lane = t & 63;
  const int row = blockIdx.x * 4 + wv;
  float lg = 0.0f;
#pragma unroll
  for (int s = 0; s < KSPLIT; ++s)
    lg += part[((size_t)row * KSPLIT + s) * E_DIM + lane];

  uint32_t jf = (uint32_t)row * 64u + (uint32_t)lane;
  uint32_t bits = jax_bits32(K1A, K1B, jf);
  float u = jax_uniform(bits);
  float inner = -logf(u + 1e-20f);       // precise log: argmax sensitivity
  float g = -logf(inner + 1e-20f);
  float w = (lg + g) * 2.5f;

  float m = w;
#pragma unroll
  for (int off = 32; off >= 1; off >>= 1) m = fmaxf(m, __shfl_xor(m, off));
  unsigned long long msk = __ballot(w == m);
  int arg = __ffsll(msk) - 1;            // first max index == jnp.argmax
  router_out[(size_t)row * E_DIM + lane] = (lane == arg) ? 1.0f : 0.0f;
  if (lane == 0) eidx[row] = arg;

  if (blockIdx.x == 0) {                 // K9 precompute (once per launch)
    float v = (t < C2BLKS) ? pminLoc[t] : 3.0e38f;
#pragma unroll
    for (int off = 32; off >= 1; off >>= 1) v = fminf(v, __shfl_xor(v, off));
    if (lane == 0) red[wv] = v;
    __syncthreads();
    if (t == 0) {
      float pmin = fminf(fminf(red[0], red[1]), fminf(red[2], red[3]));
      float tt = pmin + 2.95f;                       // 0.05 safety slack
      float delta = __expf(-__expf(tt));
      delta = fminf(fmaxf(delta, 1.2e-7f), 0.5f);    // NaN-safe, Ku < 2^23
      uint32_t Ku = (uint32_t)((1.0f - delta) * 8388608.0f);
      *K9out = Ku << 9;
    }
  }
}

// ---------------------------------------------------------------------------
// Kernel D: 45M-element gumbel-sigmoid binarize with bits-space fast path.
// 8 elems/thread (was 4): halves per-element setup overhead; two dwordx4 nt
// stores.  Grid exactly BIN_N/2048 = 22016.  M_DIM % 8 == 0 so an 8-group
// never crosses a row.  Output is 0 only if u > 1 - exp(-exp(pre+3));
// compare raw bits vs precomputed K9 (uniform scalar load).
// ---------------------------------------------------------------------------
__device__ inline float decide(float pre, uint32_t bits) {
  float u = jax_uniform(bits);
  float om = 1.0f - u;                 // exact for u >= 0.5 (Sterbenz)
  float e = -__logf(om);
  float gum = -__logf(e);              // e==0 -> +inf -> 1
  float z = pre + gum + 3.0f;
  return (z > 0.0f) ? 1.0f : 0.0f;
}

__global__ __launch_bounds__(256) void krnD(const float* __restrict__ P,
                                            const int* __restrict__ eidx,
                                            const uint32_t* __restrict__ K9p,
                                            float* __restrict__ out,
                                            uint32_t K2A, uint32_t K2B) {
  const uint32_t K9 = *K9p;                      // uniform (scalar) load

  uint32_t g = (blockIdx.x * 256u + threadIdx.x) * 8u;
  uint32_t b[8];
#pragma unroll
  for (int j = 0; j < 8; ++j) b[j] = jax_bits32(K2A, K2B, g + (uint32_t)j);
  floatx4 r0 = {1.0f, 1.0f, 1.0f, 1.0f};
  floatx4 r1 = {1.0f, 1.0f, 1.0f, 1.0f};
  uint32_t mx = 0u;
#pragma unroll
  for (int j = 0; j < 8; ++j) mx = max(mx, b[j]);
  if (mx >= K9) {                                // rare
    uint32_t row = g / (uint32_t)M_DIM;          // 8 elems share a row
    uint32_t m = g - row * (uint32_t)M_DIM;
    const float* pp = &P[(size_t)eidx[row] * M_DIM + m];
    if (b[0] >= K9) r0.x = decide(pp[0], b[0]);
    if (b[1] >= K9) r0.y = decide(pp[1], b[1]);
    if (b[2] >= K9) r0.z = decide(pp[2], b[2]);
    if (b[3] >= K9) r0.w = decide(pp[3], b[3]);
    if (b[4] >= K9) r1.x = decide(pp[4], b[4]);
    if (b[5] >= K9) r1.y = decide(pp[5], b[5]);
    if (b[6] >= K9) r1.z = decide(pp[6], b[6]);
    if (b[7] >= K9) r1.w = decide(pp[7], b[7]);
  }
  __builtin_nontemporal_store(r0, (floatx4*)&out[g]);
  __builtin_nontemporal_store(r1, (floatx4*)&out[g + 4]);
}

// ---------------------------------------------------------------------------
extern "C" void kernel_launch(void* const* d_in, const int* in_sizes, int n_in,
                              void* d_out, int out_size, void* d_ws, size_t ws_size,
                              hipStream_t stream) {
  const float* x    = (const float*)d_in[0];
  const float* rnn  = (const float*)d_in[1];
  const float* Wr   = (const float*)d_in[2];
  const float* Wd   = (const float*)d_in[3];
  const float* lnw  = (const float*)d_in[4];
  const float* lnb  = (const float*)d_in[5];
  float* out = (float*)d_out;

  // k1, k2 = split(key(42)) -- foldlike split (verified prior session)
  uint32_t K1A, K1B, K2A, K2B;
  tf2x32(0u, 42u, 0u, 0u, K1A, K1B);
  tf2x32(0u, 42u, 0u, 1u, K2A, K2B);

  // workspace (ws): small buffers only.  Logit partials (33.5 MB) live in
  // the binary region of d_out, which krnD fully overwrites afterwards.
  char* ws = (char*)d_ws;
  int*      eidx    = (int*)ws;                       // 16 KB
  float*    P       = (float*)(ws + 65536);           // 2.82 MB (16B aligned)
  float*    pminLoc = (float*)(ws + 2990080);         // 688 B
  uint32_t* K9u     = (uint32_t*)(ws + 2991104);      // 4 B

  float* part = out;                      // scratch inside binary region
  float* router_out = out + (size_t)BIN_N;

  krnAC2<<<C2BLKS + 512, 256, 0, stream>>>(x, Wr, part, rnn, lnw, lnb, Wd, P, pminLoc);
  krnB<<<1024, 256, 0, stream>>>(part, router_out, eidx, pminLoc, K9u, K1A, K1B);
  krnD<<<22016, 256, 0, stream>>>(P, eidx, K9u, out, K2A, K2B);
}